// Round 6
// baseline (232.420 us; speedup 1.0000x reference)
//
#include <hip/hip_runtime.h>

#define NB 128
#define NM 1024
#define NK 32
#define NS 12                   // per-quarter survivor slots (avg ~7.6; P(>12)~3%)
#define CUT2 25.0f
#define CUT2_BITS 0x41C80000u   // bit pattern of 25.0f
#define KEYMASK   0xFFFFFC00u   // top 22 bits d2, low 10 bits index
#define INV_CELL  (1.0f/5.2f)   // 5x5x5 cells of 5.2 >= cutoff
#define NCELL3    125

// workspace layout (bytes)
#define OFF_ORIG   (2u << 20)                 // origid   256 KB
#define OFF_STARTS (OFF_ORIG + (256u << 10))  // startsg   32 KB
#define OFF_INV    (OFF_STARTS + (32u << 10)) // invpos   256 KB
#define OFF_KEYS   (OFF_INV + (256u << 10))   // keys16   8.39 MB
#define WS_NEEDED  (OFF_KEYS + (size_t)NB * NM * NK * 2)

typedef unsigned int   u32;
typedef unsigned short u16;
typedef float vf4 __attribute__((ext_vector_type(4)));

// Prepass: bin atoms into 125 cells per molecule, write cell-sorted scan-form
// coords {-2x,-2y,-2z,|p|^2} + origid + invpos + cell-start table.
__global__ __launch_bounds__(256) void pack_bin(const float* __restrict__ pos,
                                                float4* __restrict__ sortedg,
                                                u16* __restrict__ origid,
                                                u16* __restrict__ invpos,
                                                u16* __restrict__ startsg)
{
  __shared__ u32 hist[NCELL3 + 1];
  __shared__ u32 starts[NCELL3 + 1];
  __shared__ u32 cur[NCELL3];
  const int tid = threadIdx.x;
  const int mb  = blockIdx.x;
  if (tid <= NCELL3) hist[tid] = 0;
  __syncthreads();

  float xx[4], yy[4], zz[4];
  int cid[4];
#pragma unroll
  for (int k = 0; k < 4; ++k) {
    int i  = k * 256 + tid;
    int gi = mb * NM + i;
    float x = pos[3*gi+0], y = pos[3*gi+1], z = pos[3*gi+2];
    xx[k] = x; yy[k] = y; zz[k] = z;
    int cx = (int)(x * INV_CELL); cx = cx > 4 ? 4 : cx;
    int cy = (int)(y * INV_CELL); cy = cy > 4 ? 4 : cy;
    int cz = (int)(z * INV_CELL); cz = cz > 4 ? 4 : cz;
    cid[k] = (cz * 5 + cy) * 5 + cx;
    atomicAdd(&hist[cid[k]], 1u);
  }
  __syncthreads();
  if (tid == 0) {
    u32 run = 0;
    for (int i = 0; i < NCELL3; ++i) { starts[i] = run; run += hist[i]; }
    starts[NCELL3] = run;                        // = 1024
  }
  __syncthreads();
  if (tid <= NCELL3) startsg[mb*(NCELL3+1) + tid] = (u16)starts[tid];
  if (tid <  NCELL3) cur[tid] = starts[tid];
  __syncthreads();
#pragma unroll
  for (int k = 0; k < 4; ++k) {
    int i = k * 256 + tid;
    u32 p = atomicAdd(&cur[cid[k]], 1u);
    float x = xx[k], y = yy[k], z = zz[k];
    sortedg[mb*NM + p] = make_float4(-2.f*x, -2.f*y, -2.f*z, x*x + y*y + z*z);
    origid[mb*NM + p]  = (u16)i;
    invpos[mb*NM + i]  = (u16)p;
  }
}

__device__ __forceinline__ void ce_asc(u32 &a, u32 &b) {
  u32 mn = a < b ? a : b;
  u32 mx = a < b ? b : a;
  a = mn; b = mx;
}

template <int N, int K, int D>
__device__ __forceinline__ void bitonic_pass(u32* r) {
#pragma unroll
  for (int i = 0; i < N; ++i)
    if ((i & D) == 0) {
      if ((i & K) == 0) ce_asc(r[i], r[i | D]);
      else              ce_asc(r[i | D], r[i]);
    }
}

// R11: select/emit split. R10's emit wrote 128B chunks at RANDOM rows (output
// keyed by orig id, threads keyed by sorted pos) -> scattered-write ceiling
// ~1.5 TB/s = the 103us floor (evidence: identical dur at occupancy 27% vs 57%
// -> bound is not per-CU execution; WRITE_SIZE inflated 118->153MB).
// SPLIT=true: select stores only a 64B u16 key row per center, COALESCED by
// sorted pos; emit_edges (thread = orig row) writes all 4 streams coalesced.
// SPLIT=false: R10 monolithic fallback for small workspace.
template <bool SPLIT>
__global__ __launch_bounds__(256, 8) void radius_knn(const float4* __restrict__ sortedg,
                                                     const u16* __restrict__ origg,
                                                     const u16* __restrict__ startsg,
                                                     u16* __restrict__ keys,
                                                     float* __restrict__ out)
{
  __shared__ u32 lmem[4096];    // 16KB: lists|rowbuf|flat|starts, later publish
  __shared__ u16 orig_s[NM];    // 2KB sorted-pos -> orig index (mono only)
  u16* lists  = (u16*)lmem;                    // [NS][256] u16 = 6KB (lmem[0..1535])
  u32* rowbuf = lmem + 1536;                   // 26 entries (rs<<16|cum)
  // lmem[1563] = C (total candidates)
  u16* flat   = (u16*)(lmem + 1568);           // 1056 u16 (4 quarters x 264)
  u16* st_s   = (u16*)(lmem + 2112);           // 126 u16 cell starts

  const int tid     = threadIdx.x;
  const int ctr     = tid & 63;
  const int quarter = tid >> 6;          // wave index
  const int molb    = blockIdx.x & 127;  // same-XCD blocks share molecule
  const int grp     = blockIdx.x >> 7;
  const int spos    = grp * 64 + ctr;    // center = sorted position
  const int molbase = molb * NM;

  if constexpr (!SPLIT)
    for (int t = tid; t < NM; t += 256) orig_s[t] = origg[molbase + t];
  if (tid <= NCELL3) st_s[tid] = startsg[molb*(NCELL3+1) + tid];

  const float4 mc  = sortedg[molbase + spos];
  const float mex = -0.5f*mc.x, mey = -0.5f*mc.y, mez = -0.5f*mc.z;
  const float mew = mc.w;

  // block cell bounds (every wave reduces over the same 64 centers)
  int cx = (int)(mex * INV_CELL); cx = cx > 4 ? 4 : cx;
  int cy = (int)(mey * INV_CELL); cy = cy > 4 ? 4 : cy;
  int cz = (int)(mez * INV_CELL); cz = cz > 4 ? 4 : cz;
  int mnx = cx, mxx = cx, mny = cy, mxy = cy, mnz = cz, mxz = cz;
#pragma unroll
  for (int m = 32; m; m >>= 1) {
    mnx = min(mnx, __shfl_xor(mnx, m, 64)); mxx = max(mxx, __shfl_xor(mxx, m, 64));
    mny = min(mny, __shfl_xor(mny, m, 64)); mxy = max(mxy, __shfl_xor(mxy, m, 64));
    mnz = min(mnz, __shfl_xor(mnz, m, 64)); mxz = max(mxz, __shfl_xor(mxz, m, 64));
  }
  __syncthreads();                                   // st_s ready

  if (quarter == 0) {                                // wave 0 builds 25 rows
    const int zlo = max(mnz-1, 0), zhi = min(mxz+1, 4);
    const int ylo = max(mny-1, 0), yhi = min(mxy+1, 4);
    const int xlo = max(mnx-1, 0), xhi = min(mxx+1, 4);
    const int rz = ctr / 5, ry = ctr % 5;            // lane -> (z,y) row
    int czc = zlo + rz, cyc = ylo + ry;
    u32 rs = 0, len = 0;
    if (ctr < 25 && czc <= zhi && cyc <= yhi) {
      int rowb = (czc*5 + cyc)*5;
      rs  = st_s[rowb + xlo];
      u32 re = st_s[rowb + xhi + 1];
      len = re - rs;
    }
    u32 incl = len;                                  // inclusive prefix-sum
#pragma unroll
    for (int d = 1; d < 32; d <<= 1) {
      u32 t = __shfl_up(incl, d, 64);
      if (ctr >= d) incl += t;
    }
    if (ctr < 25)  rowbuf[ctr] = (rs << 16) | (incl - len);
    if (ctr == 24) { rowbuf[25] = incl; lmem[1563] = incl; }
  }
  __syncthreads();

  const int C  = (int)lmem[1563];
  const int C4 = (C + 15) & ~15;                     // pad: equal mult-of-4 per quarter
  for (int p = tid; p < C; p += 256) {               // flat, deinterleaved mod 4
    int r = 0;
    while (p >= (int)(rowbuf[r+1] & 0xFFFFu)) ++r;
    u32 e = rowbuf[r];
    int j = (int)(e >> 16) + (p - (int)(e & 0xFFFFu));
    flat[(p & 3) * 264 + (p >> 2)] = (u16)j;
  }
  for (int p = C + tid; p < C4; p += 256) flat[(p & 3) * 264 + (p >> 2)] = 0xFFFFu;
  __syncthreads();

  // ---- phase 1: scan ~C/4 candidates per quarter (broadcast loads) ----
  int cnt = 0;
  const u16* fl = flat + quarter * 264;
  const int T = C4 >> 4;
  for (int g = 0; g < T; ++g) {
    uint2 jj = *((const uint2*)(fl + 4*g));          // ds_read_b64, wave-uniform
    int j0 = jj.x & 0xFFFF, j1 = jj.x >> 16;
    int j2 = jj.y & 0xFFFF, j3 = jj.y >> 16;
    float4 c0 = sortedg[molbase + (j0 & 1023)];
    float4 c1 = sortedg[molbase + (j1 & 1023)];
    float4 c2 = sortedg[molbase + (j2 & 1023)];
    float4 c3 = sortedg[molbase + (j3 & 1023)];
#define PROC(cj, jv)                                                        \
    {                                                                       \
      float d2 = __builtin_fmaf(mex, cj.x, __builtin_fmaf(mey, cj.y,        \
                 __builtin_fmaf(mez, cj.z, mew + cj.w)));                   \
      d2 = (jv < 1024) ? d2 : 1.0e30f;  /* pads fail */                     \
      int slot = cnt < NS ? cnt : (NS - 1);                                 \
      lists[slot * 256 + tid] = (u16)(jv & 1023);                           \
      cnt += (d2 <= CUT2) ? 1 : 0;                                          \
    }
    PROC(c0, j0) PROC(c1, j1) PROC(c2, j2) PROC(c3, j3)
#undef PROC
  }
  if (cnt > NS) cnt = NS;

  // ---- phase 2: keys + bitonic sort 16 (12 real + 4 pads) ----
  const u32 PADK = 0x7F800000u | (u32)spos;   // +inf self-pad, sorts last
  u32 r[32];
#pragma unroll
  for (int k = 0; k < 16; ++k) {
    u32 key = PADK;
    if (k < cnt) {
      int j = lists[k * 256 + tid];
      float4 cj = sortedg[molbase + j];       // per-lane gather (L2-resident)
      float d2 = fmaxf(__builtin_fmaf(mex, cj.x,
                  __builtin_fmaf(mey, cj.y,
                  __builtin_fmaf(mez, cj.z, mew + cj.w))), 0.f);
      key = (__float_as_uint(d2) & KEYMASK) | (u32)j;
    }
    r[k] = key;
  }
  bitonic_pass<16, 2, 1>(r);
  bitonic_pass<16, 4, 2>(r); bitonic_pass<16, 4, 1>(r);
  bitonic_pass<16, 8, 4>(r); bitonic_pass<16, 8, 2>(r); bitonic_pass<16, 8, 1>(r);
  bitonic_pass<16,16, 8>(r); bitonic_pass<16,16, 4>(r); bitonic_pass<16,16, 2>(r); bitonic_pass<16,16, 1>(r);

  // ---- phase 3a: symmetric pair merge (q0<->q1, q2<->q3), 16 keys ----
  __syncthreads();                       // lists/flat dead; lmem = publish buf
  {
    u32* myp = lmem + quarter * 1024 + ctr * 16;
#pragma unroll
    for (int k = 0; k < 16; ++k) myp[(k + ctr) & 15] = r[k];   // bank-swizzled
  }
  __syncthreads();
  if (!SPLIT || (quarter & 1) == 0) {    // SPLIT: only publishers need pair-32
    u32* op = lmem + (quarter ^ 1) * 1024 + ctr * 16;
#pragma unroll
    for (int i = 0; i < 16; ++i) r[16 + i] = op[((15 - i) + ctr) & 15]; // desc
    bitonic_pass<32,32,16>(r); bitonic_pass<32,32, 8>(r); bitonic_pass<32,32, 4>(r);
    bitonic_pass<32,32, 2>(r); bitonic_pass<32,32, 1>(r);
  }

  // ---- phase 3b: cross-pair merge ----
  __syncthreads();
  const int pairId = quarter >> 1;
  if ((quarter & 1) == 0) {
    u32* pp = lmem + pairId * 2048 + ctr * 32;
#pragma unroll
    for (int k = 0; k < 32; ++k) pp[(k + ctr) & 31] = r[k];
  }
  __syncthreads();
  if (!SPLIT || quarter == 0) {          // SPLIT: only q0 needs the final 32
    u32* opp = lmem + (1 - pairId) * 2048 + ctr * 32;
#pragma unroll
    for (int t = 0; t < 32; ++t) {
      u32 v = opp[((31 - t) + ctr) & 31];            // other pair, descending
      r[t] = r[t] < v ? r[t] : v;                    // lower half of bitonic-64
    }
    bitonic_pass<32,32,16>(r); bitonic_pass<32,32, 8>(r); bitonic_pass<32,32, 4>(r);
    bitonic_pass<32,32, 2>(r); bitonic_pass<32,32, 1>(r);
  }

  if constexpr (SPLIT) {
    // ---- phase 4 (split): q0 stores packed u16 keys, coalesced by spos ----
    if (quarter == 0) {
      u32 pk[16];
#pragma unroll
      for (int i = 0; i < 16; ++i) {
        u32 klo = r[2*i], khi = r[2*i+1];
        u32 plo = (((klo & KEYMASK) <= CUT2_BITS) ? 1024u : 0u) | (klo & 1023u);
        u32 phi = (((khi & KEYMASK) <= CUT2_BITS) ? 1024u : 0u) | (khi & 1023u);
        pk[i] = plo | (phi << 16);
      }
      uint4* kp = (uint4*)(keys + (size_t)(molbase + spos) * 32);
#pragma unroll
      for (int i = 0; i < 4; ++i)
        kp[i] = make_uint4(pk[4*i], pk[4*i+1], pk[4*i+2], pk[4*i+3]);
    }
    return;
  } else {
    // ---- phase 4 (mono, R10): scattered emit, one role per wave ----
    const int mloc = orig_s[spos];
    const int c = molbase + mloc;
    const long long E = (long long)NB * NM * NK;
    const float base = (float)molbase;
    const float nmex = -mex, nmey = -mey, nmez = -mez;

    if (quarter == 0) {                    // src + dst
      vf4* ps = (vf4*)(out       + (size_t)c * NK);
      vf4* pd = (vf4*)(out +   E + (size_t)c * NK);
      const float fc = (float)c;
      const vf4 dstv = {fc, fc, fc, fc};
#pragma unroll
      for (int q = 0; q < 8; ++q) {
        float sv[4];
#pragma unroll
        for (int u = 0; u < 4; ++u) {
          int idx = (int)(r[4*q + u] & 1023u);
          sv[u] = base + (float)orig_s[idx];
        }
        ps[q] = (vf4){sv[0], sv[1], sv[2], sv[3]};
        pd[q] = dstv;
      }
    } else if (quarter == 1) {             // weights
      vf4* pw = (vf4*)(out + 2*E + (size_t)c * NK);
#pragma unroll
      for (int q = 0; q < 8; ++q) {
        float wv[4];
#pragma unroll
        for (int u = 0; u < 4; ++u) {
          u32 key = r[4*q + u];
          int idx = (int)(key & 1023u);
          float4 cj = sortedg[molbase + idx];
          bool valid = (key & KEYMASK) <= CUT2_BITS;
          float vx = __builtin_fmaf(-0.5f, cj.x, nmex);
          float vy = __builtin_fmaf(-0.5f, cj.y, nmey);
          float vz = __builtin_fmaf(-0.5f, cj.z, nmez);
          bool wm  = valid && (idx != spos);
          float d2s = vx*vx + vy*vy + vz*vz;
          wv[u] = wm ? sqrtf(d2s) : 0.0f;
        }
        pw[q] = (vf4){wv[0], wv[1], wv[2], wv[3]};
      }
    } else if (quarter == 2) {             // edge vectors 0..15
      vf4* pv = (vf4*)(out + 3*E + (size_t)c * NK * 3);
#pragma unroll
      for (int q = 0; q < 4; ++q) {
        float vv[12];
#pragma unroll
        for (int u = 0; u < 4; ++u) {
          int idx = (int)(r[4*q + u] & 1023u);
          float4 cj = sortedg[molbase + idx];
          vv[3*u+0] = __builtin_fmaf(-0.5f, cj.x, nmex);
          vv[3*u+1] = __builtin_fmaf(-0.5f, cj.y, nmey);
          vv[3*u+2] = __builtin_fmaf(-0.5f, cj.z, nmez);
        }
        pv[3*q+0] = (vf4){vv[0], vv[1], vv[2],  vv[3]};
        pv[3*q+1] = (vf4){vv[4], vv[5], vv[6],  vv[7]};
        pv[3*q+2] = (vf4){vv[8], vv[9], vv[10], vv[11]};
      }
    } else {                               // edge vectors 16..31
      vf4* pv = (vf4*)(out + 3*E + (size_t)c * NK * 3) + 12;
#pragma unroll
      for (int q = 0; q < 4; ++q) {
        float vv[12];
#pragma unroll
        for (int u = 0; u < 4; ++u) {
          int idx = (int)(r[16 + 4*q + u] & 1023u);
          float4 cj = sortedg[molbase + idx];
          vv[3*u+0] = __builtin_fmaf(-0.5f, cj.x, nmex);
          vv[3*u+1] = __builtin_fmaf(-0.5f, cj.y, nmey);
          vv[3*u+2] = __builtin_fmaf(-0.5f, cj.z, nmez);
        }
        pv[3*q+0] = (vf4){vv[0], vv[1], vv[2],  vv[3]};
        pv[3*q+1] = (vf4){vv[4], vv[5], vv[6],  vv[7]};
        pv[3*q+2] = (vf4){vv[8], vv[9], vv[10], vv[11]};
      }
    }
  }
}

// Emit: thread = ORIGINAL row -> all 4 output streams perfectly coalesced.
// Per row: 1 u16 invpos read (coalesced), 4 divergent uint4 key loads (64B),
// 32 float4 coord gathers + 32 u16 origid gathers (16KB+2KB, L1/L2-resident).
__global__ __launch_bounds__(256) void emit_edges(const float4* __restrict__ sortedg,
                                                  const u16* __restrict__ origg,
                                                  const u16* __restrict__ invpos,
                                                  const u16* __restrict__ keys,
                                                  float* __restrict__ out)
{
  const int r  = blockIdx.x * 256 + threadIdx.x;   // orig row (= dst id)
  const int mb = r >> 10;
  const int molbase = mb << 10;
  const int spos = invpos[r];
  const float4 mc = sortedg[molbase + spos];
  const float mex = -0.5f*mc.x, mey = -0.5f*mc.y, mez = -0.5f*mc.z;
  const float nmex = -mex, nmey = -mey, nmez = -mez;
  const long long E = (long long)NB * NM * NK;
  const float base = (float)molbase;

  const uint4* kp = (const uint4*)(keys + (size_t)(molbase + spos) * 32);
  u32 wds[16];
#pragma unroll
  for (int i = 0; i < 4; ++i) {
    uint4 kv = kp[i];
    wds[4*i+0] = kv.x; wds[4*i+1] = kv.y; wds[4*i+2] = kv.z; wds[4*i+3] = kv.w;
  }

  vf4* ps = (vf4*)(out       + (size_t)r * NK);
  vf4* pd = (vf4*)(out +   E + (size_t)r * NK);
  vf4* pw = (vf4*)(out + 2*E + (size_t)r * NK);
  vf4* pv = (vf4*)(out + 3*E + (size_t)r * NK * 3);
  const float fr = (float)r;
  const vf4 dstv = {fr, fr, fr, fr};

#pragma unroll
  for (int q = 0; q < 8; ++q) {
    float sv[4], wv[4], vvv[12];
#pragma unroll
    for (int u = 0; u < 4; ++u) {
      u32 key = (wds[2*q + (u >> 1)] >> ((u & 1) * 16)) & 0xFFFFu;
      int idx = (int)(key & 1023u);
      bool valid = (key & 1024u) != 0;
      float4 cj = sortedg[molbase + idx];
      float vx = __builtin_fmaf(-0.5f, cj.x, nmex);
      float vy = __builtin_fmaf(-0.5f, cj.y, nmey);
      float vz = __builtin_fmaf(-0.5f, cj.z, nmez);
      bool wm  = valid && (idx != spos);
      float d2s = vx*vx + vy*vy + vz*vz;
      wv[u] = wm ? sqrtf(d2s) : 0.0f;
      sv[u] = base + (float)origg[molbase + idx];
      vvv[3*u+0] = vx; vvv[3*u+1] = vy; vvv[3*u+2] = vz;
    }
    ps[q] = (vf4){sv[0], sv[1], sv[2], sv[3]};
    pd[q] = dstv;
    pw[q] = (vf4){wv[0], wv[1], wv[2], wv[3]};
    pv[3*q+0] = (vf4){vvv[0], vvv[1], vvv[2],  vvv[3]};
    pv[3*q+1] = (vf4){vvv[4], vvv[5], vvv[6],  vvv[7]};
    pv[3*q+2] = (vf4){vvv[8], vvv[9], vvv[10], vvv[11]};
  }
}

extern "C" void kernel_launch(void* const* d_in, const int* in_sizes, int n_in,
                              void* d_out, int out_size, void* d_ws, size_t ws_size,
                              hipStream_t stream) {
  const float* pos = (const float*)d_in[0];
  float* out = (float*)d_out;
  float4* sortedg = (float4*)d_ws;                           // 2 MB
  u16* origid  = (u16*)((char*)d_ws + OFF_ORIG);
  u16* startsg = (u16*)((char*)d_ws + OFF_STARTS);
  u16* invpos  = (u16*)((char*)d_ws + OFF_INV);
  u16* keys    = (u16*)((char*)d_ws + OFF_KEYS);

  hipLaunchKernelGGL(pack_bin, dim3(NB), dim3(256), 0, stream,
                     pos, sortedg, origid, invpos, startsg);
  if (ws_size >= WS_NEEDED) {
    hipLaunchKernelGGL((radius_knn<true>), dim3(NB * (NM / 64)), dim3(256), 0, stream,
                       sortedg, origid, startsg, keys, out);
    hipLaunchKernelGGL(emit_edges, dim3((NB * NM) / 256), dim3(256), 0, stream,
                       sortedg, origid, invpos, keys, out);
  } else {
    hipLaunchKernelGGL((radius_knn<false>), dim3(NB * (NM / 64)), dim3(256), 0, stream,
                       sortedg, origid, startsg, keys, out);
  }
}

// Round 7
// 171.434 us; speedup vs baseline: 1.3557x; 1.3557x over previous
//
#include <hip/hip_runtime.h>

#define NB 128
#define NM 1024
#define NK 32
#define NS 12                   // per-quarter survivor slots (avg ~7.6; P(>12)~3%)
#define CUT2 25.0f
#define CUT2_BITS 0x41C80000u   // bit pattern of 25.0f
#define KEYMASK   0xFFFFFC00u   // top 22 bits d2, low 10 bits index
#define INV_CELL  (1.0f/5.2f)   // 5x5x5 cells of 5.2 >= cutoff
#define NCELL3    125

// workspace layout (bytes)
#define OFF_ORIG   (2u << 20)                 // origid   256 KB
#define OFF_STARTS (OFF_ORIG + (256u << 10))  // startsg   32 KB
#define OFF_INV    (OFF_STARTS + (32u << 10)) // invpos   256 KB
#define OFF_KEYS   (OFF_INV + (256u << 10))   // keys16   8.39 MB
#define WS_NEEDED  (OFF_KEYS + (size_t)NB * NM * NK * 2)

typedef unsigned int   u32;
typedef unsigned short u16;
typedef float vf4 __attribute__((ext_vector_type(4)));

// Prepass: bin atoms into 125 cells per molecule, write cell-sorted scan-form
// coords {-2x,-2y,-2z,|p|^2} + origid + invpos + cell-start table.
__global__ __launch_bounds__(256) void pack_bin(const float* __restrict__ pos,
                                                float4* __restrict__ sortedg,
                                                u16* __restrict__ origid,
                                                u16* __restrict__ invpos,
                                                u16* __restrict__ startsg)
{
  __shared__ u32 hist[NCELL3 + 1];
  __shared__ u32 starts[NCELL3 + 1];
  __shared__ u32 cur[NCELL3];
  const int tid = threadIdx.x;
  const int mb  = blockIdx.x;
  if (tid <= NCELL3) hist[tid] = 0;
  __syncthreads();

  float xx[4], yy[4], zz[4];
  int cid[4];
#pragma unroll
  for (int k = 0; k < 4; ++k) {
    int i  = k * 256 + tid;
    int gi = mb * NM + i;
    float x = pos[3*gi+0], y = pos[3*gi+1], z = pos[3*gi+2];
    xx[k] = x; yy[k] = y; zz[k] = z;
    int cx = (int)(x * INV_CELL); cx = cx > 4 ? 4 : cx;
    int cy = (int)(y * INV_CELL); cy = cy > 4 ? 4 : cy;
    int cz = (int)(z * INV_CELL); cz = cz > 4 ? 4 : cz;
    cid[k] = (cz * 5 + cy) * 5 + cx;
    atomicAdd(&hist[cid[k]], 1u);
  }
  __syncthreads();
  if (tid == 0) {
    u32 run = 0;
    for (int i = 0; i < NCELL3; ++i) { starts[i] = run; run += hist[i]; }
    starts[NCELL3] = run;                        // = 1024
  }
  __syncthreads();
  if (tid <= NCELL3) startsg[mb*(NCELL3+1) + tid] = (u16)starts[tid];
  if (tid <  NCELL3) cur[tid] = starts[tid];
  __syncthreads();
#pragma unroll
  for (int k = 0; k < 4; ++k) {
    int i = k * 256 + tid;
    u32 p = atomicAdd(&cur[cid[k]], 1u);
    float x = xx[k], y = yy[k], z = zz[k];
    sortedg[mb*NM + p] = make_float4(-2.f*x, -2.f*y, -2.f*z, x*x + y*y + z*z);
    origid[mb*NM + p]  = (u16)i;
    invpos[mb*NM + i]  = (u16)p;
  }
}

__device__ __forceinline__ void ce_asc(u32 &a, u32 &b) {
  u32 mn = a < b ? a : b;
  u32 mx = a < b ? b : a;
  a = mn; b = mx;
}

template <int N, int K, int D>
__device__ __forceinline__ void bitonic_pass(u32* r) {
#pragma unroll
  for (int i = 0; i < N; ++i)
    if ((i & D) == 0) {
      if ((i & K) == 0) ce_asc(r[i], r[i | D]);
      else              ce_asc(r[i | D], r[i]);
    }
}

// R12: select unchanged (R11, ~52us); emit restructured thread-per-EDGE.
// R11's emit was thread-per-row: 512 blocks (2/CU, grid-limited, occ 16%),
// 32 serial gathers/thread (VALUBusy 3.8%), and 128B-lane-stride store
// instructions -> partial-line eviction doubled WRITE_SIZE (194MB vs 100.6
// ideal). Thread-per-edge: 16384 blocks, all stores instruction-coalesced
// (s/d/w: 4B/lane contiguous; vec: 12B/lane contiguous), 1 gather/thread.
template <bool SPLIT>
__global__ __launch_bounds__(256, 8) void radius_knn(const float4* __restrict__ sortedg,
                                                     const u16* __restrict__ origg,
                                                     const u16* __restrict__ startsg,
                                                     u16* __restrict__ keys,
                                                     float* __restrict__ out)
{
  __shared__ u32 lmem[4096];    // 16KB: lists|rowbuf|flat|starts, later publish
  __shared__ u16 orig_s[NM];    // 2KB sorted-pos -> orig index (mono only)
  u16* lists  = (u16*)lmem;                    // [NS][256] u16 = 6KB (lmem[0..1535])
  u32* rowbuf = lmem + 1536;                   // 26 entries (rs<<16|cum)
  // lmem[1563] = C (total candidates)
  u16* flat   = (u16*)(lmem + 1568);           // 1056 u16 (4 quarters x 264)
  u16* st_s   = (u16*)(lmem + 2112);           // 126 u16 cell starts

  const int tid     = threadIdx.x;
  const int ctr     = tid & 63;
  const int quarter = tid >> 6;          // wave index
  const int molb    = blockIdx.x & 127;  // same-XCD blocks share molecule
  const int grp     = blockIdx.x >> 7;
  const int spos    = grp * 64 + ctr;    // center = sorted position
  const int molbase = molb * NM;

  if constexpr (!SPLIT)
    for (int t = tid; t < NM; t += 256) orig_s[t] = origg[molbase + t];
  if (tid <= NCELL3) st_s[tid] = startsg[molb*(NCELL3+1) + tid];

  const float4 mc  = sortedg[molbase + spos];
  const float mex = -0.5f*mc.x, mey = -0.5f*mc.y, mez = -0.5f*mc.z;
  const float mew = mc.w;

  // block cell bounds (every wave reduces over the same 64 centers)
  int cx = (int)(mex * INV_CELL); cx = cx > 4 ? 4 : cx;
  int cy = (int)(mey * INV_CELL); cy = cy > 4 ? 4 : cy;
  int cz = (int)(mez * INV_CELL); cz = cz > 4 ? 4 : cz;
  int mnx = cx, mxx = cx, mny = cy, mxy = cy, mnz = cz, mxz = cz;
#pragma unroll
  for (int m = 32; m; m >>= 1) {
    mnx = min(mnx, __shfl_xor(mnx, m, 64)); mxx = max(mxx, __shfl_xor(mxx, m, 64));
    mny = min(mny, __shfl_xor(mny, m, 64)); mxy = max(mxy, __shfl_xor(mxy, m, 64));
    mnz = min(mnz, __shfl_xor(mnz, m, 64)); mxz = max(mxz, __shfl_xor(mxz, m, 64));
  }
  __syncthreads();                                   // st_s ready

  if (quarter == 0) {                                // wave 0 builds 25 rows
    const int zlo = max(mnz-1, 0), zhi = min(mxz+1, 4);
    const int ylo = max(mny-1, 0), yhi = min(mxy+1, 4);
    const int xlo = max(mnx-1, 0), xhi = min(mxx+1, 4);
    const int rz = ctr / 5, ry = ctr % 5;            // lane -> (z,y) row
    int czc = zlo + rz, cyc = ylo + ry;
    u32 rs = 0, len = 0;
    if (ctr < 25 && czc <= zhi && cyc <= yhi) {
      int rowb = (czc*5 + cyc)*5;
      rs  = st_s[rowb + xlo];
      u32 re = st_s[rowb + xhi + 1];
      len = re - rs;
    }
    u32 incl = len;                                  // inclusive prefix-sum
#pragma unroll
    for (int d = 1; d < 32; d <<= 1) {
      u32 t = __shfl_up(incl, d, 64);
      if (ctr >= d) incl += t;
    }
    if (ctr < 25)  rowbuf[ctr] = (rs << 16) | (incl - len);
    if (ctr == 24) { rowbuf[25] = incl; lmem[1563] = incl; }
  }
  __syncthreads();

  const int C  = (int)lmem[1563];
  const int C4 = (C + 15) & ~15;                     // pad: equal mult-of-4 per quarter
  for (int p = tid; p < C; p += 256) {               // flat, deinterleaved mod 4
    int r = 0;
    while (p >= (int)(rowbuf[r+1] & 0xFFFFu)) ++r;
    u32 e = rowbuf[r];
    int j = (int)(e >> 16) + (p - (int)(e & 0xFFFFu));
    flat[(p & 3) * 264 + (p >> 2)] = (u16)j;
  }
  for (int p = C + tid; p < C4; p += 256) flat[(p & 3) * 264 + (p >> 2)] = 0xFFFFu;
  __syncthreads();

  // ---- phase 1: scan ~C/4 candidates per quarter (broadcast loads) ----
  int cnt = 0;
  const u16* fl = flat + quarter * 264;
  const int T = C4 >> 4;
  for (int g = 0; g < T; ++g) {
    uint2 jj = *((const uint2*)(fl + 4*g));          // ds_read_b64, wave-uniform
    int j0 = jj.x & 0xFFFF, j1 = jj.x >> 16;
    int j2 = jj.y & 0xFFFF, j3 = jj.y >> 16;
    float4 c0 = sortedg[molbase + (j0 & 1023)];
    float4 c1 = sortedg[molbase + (j1 & 1023)];
    float4 c2 = sortedg[molbase + (j2 & 1023)];
    float4 c3 = sortedg[molbase + (j3 & 1023)];
#define PROC(cj, jv)                                                        \
    {                                                                       \
      float d2 = __builtin_fmaf(mex, cj.x, __builtin_fmaf(mey, cj.y,        \
                 __builtin_fmaf(mez, cj.z, mew + cj.w)));                   \
      d2 = (jv < 1024) ? d2 : 1.0e30f;  /* pads fail */                     \
      int slot = cnt < NS ? cnt : (NS - 1);                                 \
      lists[slot * 256 + tid] = (u16)(jv & 1023);                           \
      cnt += (d2 <= CUT2) ? 1 : 0;                                          \
    }
    PROC(c0, j0) PROC(c1, j1) PROC(c2, j2) PROC(c3, j3)
#undef PROC
  }
  if (cnt > NS) cnt = NS;

  // ---- phase 2: keys + bitonic sort 16 (12 real + 4 pads) ----
  const u32 PADK = 0x7F800000u | (u32)spos;   // +inf self-pad, sorts last
  u32 r[32];
#pragma unroll
  for (int k = 0; k < 16; ++k) {
    u32 key = PADK;
    if (k < cnt) {
      int j = lists[k * 256 + tid];
      float4 cj = sortedg[molbase + j];       // per-lane gather (L2-resident)
      float d2 = fmaxf(__builtin_fmaf(mex, cj.x,
                  __builtin_fmaf(mey, cj.y,
                  __builtin_fmaf(mez, cj.z, mew + cj.w))), 0.f);
      key = (__float_as_uint(d2) & KEYMASK) | (u32)j;
    }
    r[k] = key;
  }
  bitonic_pass<16, 2, 1>(r);
  bitonic_pass<16, 4, 2>(r); bitonic_pass<16, 4, 1>(r);
  bitonic_pass<16, 8, 4>(r); bitonic_pass<16, 8, 2>(r); bitonic_pass<16, 8, 1>(r);
  bitonic_pass<16,16, 8>(r); bitonic_pass<16,16, 4>(r); bitonic_pass<16,16, 2>(r); bitonic_pass<16,16, 1>(r);

  // ---- phase 3a: symmetric pair merge (q0<->q1, q2<->q3), 16 keys ----
  __syncthreads();                       // lists/flat dead; lmem = publish buf
  {
    u32* myp = lmem + quarter * 1024 + ctr * 16;
#pragma unroll
    for (int k = 0; k < 16; ++k) myp[(k + ctr) & 15] = r[k];   // bank-swizzled
  }
  __syncthreads();
  if (!SPLIT || (quarter & 1) == 0) {    // SPLIT: only publishers need pair-32
    u32* op = lmem + (quarter ^ 1) * 1024 + ctr * 16;
#pragma unroll
    for (int i = 0; i < 16; ++i) r[16 + i] = op[((15 - i) + ctr) & 15]; // desc
    bitonic_pass<32,32,16>(r); bitonic_pass<32,32, 8>(r); bitonic_pass<32,32, 4>(r);
    bitonic_pass<32,32, 2>(r); bitonic_pass<32,32, 1>(r);
  }

  // ---- phase 3b: cross-pair merge ----
  __syncthreads();
  const int pairId = quarter >> 1;
  if ((quarter & 1) == 0) {
    u32* pp = lmem + pairId * 2048 + ctr * 32;
#pragma unroll
    for (int k = 0; k < 32; ++k) pp[(k + ctr) & 31] = r[k];
  }
  __syncthreads();
  if (!SPLIT || quarter == 0) {          // SPLIT: only q0 needs the final 32
    u32* opp = lmem + (1 - pairId) * 2048 + ctr * 32;
#pragma unroll
    for (int t = 0; t < 32; ++t) {
      u32 v = opp[((31 - t) + ctr) & 31];            // other pair, descending
      r[t] = r[t] < v ? r[t] : v;                    // lower half of bitonic-64
    }
    bitonic_pass<32,32,16>(r); bitonic_pass<32,32, 8>(r); bitonic_pass<32,32, 4>(r);
    bitonic_pass<32,32, 2>(r); bitonic_pass<32,32, 1>(r);
  }

  if constexpr (SPLIT) {
    // ---- phase 4 (split): q0 stores packed u16 keys, coalesced by spos ----
    if (quarter == 0) {
      u32 pk[16];
#pragma unroll
      for (int i = 0; i < 16; ++i) {
        u32 klo = r[2*i], khi = r[2*i+1];
        u32 plo = (((klo & KEYMASK) <= CUT2_BITS) ? 1024u : 0u) | (klo & 1023u);
        u32 phi = (((khi & KEYMASK) <= CUT2_BITS) ? 1024u : 0u) | (khi & 1023u);
        pk[i] = plo | (phi << 16);
      }
      uint4* kp = (uint4*)(keys + (size_t)(molbase + spos) * 32);
#pragma unroll
      for (int i = 0; i < 4; ++i)
        kp[i] = make_uint4(pk[4*i], pk[4*i+1], pk[4*i+2], pk[4*i+3]);
    }
    return;
  } else {
    // ---- phase 4 (mono, R10): scattered emit, one role per wave ----
    const int mloc = orig_s[spos];
    const int c = molbase + mloc;
    const long long E = (long long)NB * NM * NK;
    const float base = (float)molbase;
    const float nmex = -mex, nmey = -mey, nmez = -mez;

    if (quarter == 0) {                    // src + dst
      vf4* ps = (vf4*)(out       + (size_t)c * NK);
      vf4* pd = (vf4*)(out +   E + (size_t)c * NK);
      const float fc = (float)c;
      const vf4 dstv = {fc, fc, fc, fc};
#pragma unroll
      for (int q = 0; q < 8; ++q) {
        float sv[4];
#pragma unroll
        for (int u = 0; u < 4; ++u) {
          int idx = (int)(r[4*q + u] & 1023u);
          sv[u] = base + (float)orig_s[idx];
        }
        ps[q] = (vf4){sv[0], sv[1], sv[2], sv[3]};
        pd[q] = dstv;
      }
    } else if (quarter == 1) {             // weights
      vf4* pw = (vf4*)(out + 2*E + (size_t)c * NK);
#pragma unroll
      for (int q = 0; q < 8; ++q) {
        float wv[4];
#pragma unroll
        for (int u = 0; u < 4; ++u) {
          u32 key = r[4*q + u];
          int idx = (int)(key & 1023u);
          float4 cj = sortedg[molbase + idx];
          bool valid = (key & KEYMASK) <= CUT2_BITS;
          float vx = __builtin_fmaf(-0.5f, cj.x, nmex);
          float vy = __builtin_fmaf(-0.5f, cj.y, nmey);
          float vz = __builtin_fmaf(-0.5f, cj.z, nmez);
          bool wm  = valid && (idx != spos);
          float d2s = vx*vx + vy*vy + vz*vz;
          wv[u] = wm ? sqrtf(d2s) : 0.0f;
        }
        pw[q] = (vf4){wv[0], wv[1], wv[2], wv[3]};
      }
    } else if (quarter == 2) {             // edge vectors 0..15
      vf4* pv = (vf4*)(out + 3*E + (size_t)c * NK * 3);
#pragma unroll
      for (int q = 0; q < 4; ++q) {
        float vv[12];
#pragma unroll
        for (int u = 0; u < 4; ++u) {
          int idx = (int)(r[4*q + u] & 1023u);
          float4 cj = sortedg[molbase + idx];
          vv[3*u+0] = __builtin_fmaf(-0.5f, cj.x, nmex);
          vv[3*u+1] = __builtin_fmaf(-0.5f, cj.y, nmey);
          vv[3*u+2] = __builtin_fmaf(-0.5f, cj.z, nmez);
        }
        pv[3*q+0] = (vf4){vv[0], vv[1], vv[2],  vv[3]};
        pv[3*q+1] = (vf4){vv[4], vv[5], vv[6],  vv[7]};
        pv[3*q+2] = (vf4){vv[8], vv[9], vv[10], vv[11]};
      }
    } else {                               // edge vectors 16..31
      vf4* pv = (vf4*)(out + 3*E + (size_t)c * NK * 3) + 12;
#pragma unroll
      for (int q = 0; q < 4; ++q) {
        float vv[12];
#pragma unroll
        for (int u = 0; u < 4; ++u) {
          int idx = (int)(r[16 + 4*q + u] & 1023u);
          float4 cj = sortedg[molbase + idx];
          vv[3*u+0] = __builtin_fmaf(-0.5f, cj.x, nmex);
          vv[3*u+1] = __builtin_fmaf(-0.5f, cj.y, nmey);
          vv[3*u+2] = __builtin_fmaf(-0.5f, cj.z, nmez);
        }
        pv[3*q+0] = (vf4){vv[0], vv[1], vv[2],  vv[3]};
        pv[3*q+1] = (vf4){vv[4], vv[5], vv[6],  vv[7]};
        pv[3*q+2] = (vf4){vv[8], vv[9], vv[10], vv[11]};
      }
    }
  }
}

// Emit: one thread per EDGE. All stores instruction-coalesced:
// src/dst/w are 4B/lane contiguous (256B per wave-instruction), vec is
// 12B/lane contiguous. Loads: invpos+keys coalesced/broadcast, one 16B
// coord gather from the L1/L2-resident 16KB molecule set.
__global__ __launch_bounds__(256) void emit_edges(const float4* __restrict__ sortedg,
                                                  const u16* __restrict__ origg,
                                                  const u16* __restrict__ invpos,
                                                  const u16* __restrict__ keys,
                                                  float* __restrict__ out)
{
  const int e = blockIdx.x * 256 + threadIdx.x;    // edge id
  const int r = e >> 5;                            // orig row (= dst id)
  const int k = e & 31;
  const int molbase = (r >> 10) << 10;
  const int spos = invpos[r];                      // broadcast within row

  const u16 key = keys[((size_t)(molbase + spos) << 5) + k];  // coalesced
  const int idx = (int)(key & 1023u);
  const bool valid = (key & 1024u) != 0;

  const float4 mc = sortedg[molbase + spos];       // broadcast within row
  const float4 cj = sortedg[molbase + idx];        // 16B gather, L1/L2-warm
  const float vx = (-0.5f*cj.x) - (-0.5f*mc.x);    // exact recovery, 1 rounding
  const float vy = (-0.5f*cj.y) - (-0.5f*mc.y);
  const float vz = (-0.5f*cj.z) - (-0.5f*mc.z);
  const bool wm = valid && (idx != spos);
  const float w = wm ? sqrtf(vx*vx + vy*vy + vz*vz) : 0.0f;

  const long long E = (long long)NB * NM * NK;
  out[e]       = (float)molbase + (float)origg[molbase + idx];  // src
  out[E + e]   = (float)r;                                      // dst
  out[2*E + e] = w;                                             // weight
  float* pv = out + 3*E + (size_t)e * 3;                        // vec
  pv[0] = vx; pv[1] = vy; pv[2] = vz;
}

extern "C" void kernel_launch(void* const* d_in, const int* in_sizes, int n_in,
                              void* d_out, int out_size, void* d_ws, size_t ws_size,
                              hipStream_t stream) {
  const float* pos = (const float*)d_in[0];
  float* out = (float*)d_out;
  float4* sortedg = (float4*)d_ws;                           // 2 MB
  u16* origid  = (u16*)((char*)d_ws + OFF_ORIG);
  u16* startsg = (u16*)((char*)d_ws + OFF_STARTS);
  u16* invpos  = (u16*)((char*)d_ws + OFF_INV);
  u16* keys    = (u16*)((char*)d_ws + OFF_KEYS);

  hipLaunchKernelGGL(pack_bin, dim3(NB), dim3(256), 0, stream,
                     pos, sortedg, origid, invpos, startsg);
  if (ws_size >= WS_NEEDED) {
    hipLaunchKernelGGL((radius_knn<true>), dim3(NB * (NM / 64)), dim3(256), 0, stream,
                       sortedg, origid, startsg, keys, out);
    hipLaunchKernelGGL(emit_edges, dim3((int)(((long long)NB * NM * NK) / 256)),
                       dim3(256), 0, stream, sortedg, origid, invpos, keys, out);
  } else {
    hipLaunchKernelGGL((radius_knn<false>), dim3(NB * (NM / 64)), dim3(256), 0, stream,
                       sortedg, origid, startsg, keys, out);
  }
}

// Round 8
// 166.895 us; speedup vs baseline: 1.3926x; 1.0272x over previous
//
#include <hip/hip_runtime.h>

#define NB 128
#define NM 1024
#define NK 32
#define NS 12                   // per-quarter survivor slots (avg ~7.6; P(>12)~3%)
#define CUT2 25.0f
#define CUT2_BITS 0x41C80000u   // bit pattern of 25.0f
#define KEYMASK   0xFFFFFC00u   // top 22 bits d2, low 10 bits index
#define INV_CELL  (1.0f/5.2f)   // 5x5x5 cells of 5.2 >= cutoff
#define NCELL3    125
#define SSTRIDE   1032          // sortedg row stride: 1024 atoms + 8 sentinels

// workspace layout (bytes)
#define OFF_ORIG   ((size_t)NB * SSTRIDE * 16)            // sortedg 2.11 MB
#define OFF_STARTS (OFF_ORIG + (size_t)(256u << 10))      // origid  256 KB
#define OFF_INV    (OFF_STARTS + (size_t)(32u << 10))     // startsg  32 KB
#define OFF_KEYS   (OFF_INV + (size_t)(256u << 10))       // invpos  256 KB
#define WS_NEEDED  (OFF_KEYS + (size_t)NB * NM * NK * 2)  // keys    8.39 MB

typedef unsigned int   u32;
typedef unsigned short u16;
typedef float vf4 __attribute__((ext_vector_type(4)));

// Prepass: bin atoms into 125 cells per molecule, write cell-sorted scan-form
// coords {-2x,-2y,-2z,|p|^2} + origid + invpos + cell-start table.
// 8 sentinel atoms (coords 1e15 -> d2 ~1e30) close each molecule's row so the
// scan's pad candidates (j=1024) fail the cutoff with NO per-candidate test.
__global__ __launch_bounds__(256) void pack_bin(const float* __restrict__ pos,
                                                float4* __restrict__ sortedg,
                                                u16* __restrict__ origid,
                                                u16* __restrict__ invpos,
                                                u16* __restrict__ startsg)
{
  __shared__ u32 hist[NCELL3 + 1];
  __shared__ u32 starts[NCELL3 + 1];
  __shared__ u32 cur[NCELL3];
  const int tid = threadIdx.x;
  const int mb  = blockIdx.x;
  if (tid <= NCELL3) hist[tid] = 0;
  __syncthreads();

  float xx[4], yy[4], zz[4];
  int cid[4];
#pragma unroll
  for (int k = 0; k < 4; ++k) {
    int i  = k * 256 + tid;
    int gi = mb * NM + i;
    float x = pos[3*gi+0], y = pos[3*gi+1], z = pos[3*gi+2];
    xx[k] = x; yy[k] = y; zz[k] = z;
    int cx = (int)(x * INV_CELL); cx = cx > 4 ? 4 : cx;
    int cy = (int)(y * INV_CELL); cy = cy > 4 ? 4 : cy;
    int cz = (int)(z * INV_CELL); cz = cz > 4 ? 4 : cz;
    cid[k] = (cz * 5 + cy) * 5 + cx;
    atomicAdd(&hist[cid[k]], 1u);
  }
  __syncthreads();
  if (tid == 0) {
    u32 run = 0;
    for (int i = 0; i < NCELL3; ++i) { starts[i] = run; run += hist[i]; }
    starts[NCELL3] = run;                        // = 1024
  }
  __syncthreads();
  if (tid <= NCELL3) startsg[mb*(NCELL3+1) + tid] = (u16)starts[tid];
  if (tid <  NCELL3) cur[tid] = starts[tid];
  __syncthreads();
#pragma unroll
  for (int k = 0; k < 4; ++k) {
    int i = k * 256 + tid;
    u32 p = atomicAdd(&cur[cid[k]], 1u);
    float x = xx[k], y = yy[k], z = zz[k];
    sortedg[mb*SSTRIDE + p] = make_float4(-2.f*x, -2.f*y, -2.f*z, x*x + y*y + z*z);
    origid[mb*NM + p]  = (u16)i;
    invpos[mb*NM + i]  = (u16)p;
  }
  if (tid < 8)                                    // sentinels
    sortedg[mb*SSTRIDE + 1024 + tid] = make_float4(-2e15f, -2e15f, -2e15f, 1e30f);
}

__device__ __forceinline__ void ce_asc(u32 &a, u32 &b) {
  u32 mn = a < b ? a : b;
  u32 mx = a < b ? b : a;
  a = mn; b = mx;
}

template <int N, int K, int D>
__device__ __forceinline__ void bitonic_pass(u32* r) {
#pragma unroll
  for (int i = 0; i < N; ++i)
    if ((i & D) == 0) {
      if ((i & K) == 0) ce_asc(r[i], r[i | D]);
      else              ce_asc(r[i | D], r[i]);
    }
}

// R13: select streamlined. (a) KEY-CARRYING lists: phase 1 stores the packed
// u32 key (clamped d2 | idx) so phase 2 is a pure LDS read — deletes 16
// per-lane random gathers + 16 fma chains per thread (keys bit-identical to
// R12's recompute). (b) sentinel pad atoms kill the per-candidate pad cndmask.
// (c) flat candidate list read 8-wide via ds_read_b128 (stride 272 = 16B-
// aligned). Merge/publish/emit machinery unchanged (proven R12).
template <bool SPLIT>
__global__ __launch_bounds__(256, 8) void radius_knn(const float4* __restrict__ sortedg,
                                                     const u16* __restrict__ origg,
                                                     const u16* __restrict__ startsg,
                                                     u16* __restrict__ keys,
                                                     float* __restrict__ out)
{
  __shared__ u32 lmem[4096];    // 16KB: lists|rowbuf|flat|starts, later publish
  __shared__ u16 orig_s[NM];    // 2KB sorted-pos -> orig index (mono only)
  u32* lists  = lmem;                          // [NS][256] u32 = 12KB (0..3071)
  u32* rowbuf = lmem + 3072;                   // 26 entries (rs<<16|cum)
  // lmem[3099] = C (total candidates)
  u16* flat   = (u16*)(lmem + 3104);           // 1088 u16 (4 quarters x 272)
  u16* st_s   = (u16*)(lmem + 3648);           // 126 u16 cell starts

  const int tid     = threadIdx.x;
  const int ctr     = tid & 63;
  const int quarter = tid >> 6;          // wave index
  const int molb    = blockIdx.x & 127;  // same-XCD blocks share molecule
  const int grp     = blockIdx.x >> 7;
  const int spos    = grp * 64 + ctr;    // center = sorted position
  const int molbase  = molb * NM;        // origg/keys stride
  const int molbaseS = molb * SSTRIDE;   // sortedg stride (with sentinels)

  if constexpr (!SPLIT)
    for (int t = tid; t < NM; t += 256) orig_s[t] = origg[molbase + t];
  if (tid <= NCELL3) st_s[tid] = startsg[molb*(NCELL3+1) + tid];

  const float4 mc  = sortedg[molbaseS + spos];
  const float mex = -0.5f*mc.x, mey = -0.5f*mc.y, mez = -0.5f*mc.z;
  const float mew = mc.w;

  // block cell bounds (every wave reduces over the same 64 centers)
  int cx = (int)(mex * INV_CELL); cx = cx > 4 ? 4 : cx;
  int cy = (int)(mey * INV_CELL); cy = cy > 4 ? 4 : cy;
  int cz = (int)(mez * INV_CELL); cz = cz > 4 ? 4 : cz;
  int mnx = cx, mxx = cx, mny = cy, mxy = cy, mnz = cz, mxz = cz;
#pragma unroll
  for (int m = 32; m; m >>= 1) {
    mnx = min(mnx, __shfl_xor(mnx, m, 64)); mxx = max(mxx, __shfl_xor(mxx, m, 64));
    mny = min(mny, __shfl_xor(mny, m, 64)); mxy = max(mxy, __shfl_xor(mxy, m, 64));
    mnz = min(mnz, __shfl_xor(mnz, m, 64)); mxz = max(mxz, __shfl_xor(mxz, m, 64));
  }
  __syncthreads();                                   // st_s ready

  if (quarter == 0) {                                // wave 0 builds 25 rows
    const int zlo = max(mnz-1, 0), zhi = min(mxz+1, 4);
    const int ylo = max(mny-1, 0), yhi = min(mxy+1, 4);
    const int xlo = max(mnx-1, 0), xhi = min(mxx+1, 4);
    const int rz = ctr / 5, ry = ctr % 5;            // lane -> (z,y) row
    int czc = zlo + rz, cyc = ylo + ry;
    u32 rs = 0, len = 0;
    if (ctr < 25 && czc <= zhi && cyc <= yhi) {
      int rowb = (czc*5 + cyc)*5;
      rs  = st_s[rowb + xlo];
      u32 re = st_s[rowb + xhi + 1];
      len = re - rs;
    }
    u32 incl = len;                                  // inclusive prefix-sum
#pragma unroll
    for (int d = 1; d < 32; d <<= 1) {
      u32 t = __shfl_up(incl, d, 64);
      if (ctr >= d) incl += t;
    }
    if (ctr < 25)  rowbuf[ctr] = (rs << 16) | (incl - len);
    if (ctr == 24) { rowbuf[25] = incl; lmem[3099] = incl; }
  }
  __syncthreads();

  const int C  = (int)lmem[3099];
  const int C4 = (C + 31) & ~31;             // pad: equal mult-of-8 per quarter
  for (int p = tid; p < C; p += 256) {       // flat, deinterleaved mod 4
    int r = 0;
    while (p >= (int)(rowbuf[r+1] & 0xFFFFu)) ++r;
    u32 e = rowbuf[r];
    int j = (int)(e >> 16) + (p - (int)(e & 0xFFFFu));
    flat[(p & 3) * 272 + (p >> 2)] = (u16)j;
  }
  for (int p = C + tid; p < C4; p += 256) flat[(p & 3) * 272 + (p >> 2)] = 1024;
  __syncthreads();

  // ---- phase 1: scan ~C/4 candidates per quarter (broadcast loads),
  //      packing keys directly into the survivor list ----
  int cnt = 0;
  const u16* fl = flat + quarter * 272;
  const int T = C4 >> 5;                     // 8 candidates per iteration
  for (int g = 0; g < T; ++g) {
    uint4 jj = *((const uint4*)(fl + 8*g));  // ds_read_b128, wave-uniform
    int j0 = jj.x & 0xFFFF, j1 = jj.x >> 16;
    int j2 = jj.y & 0xFFFF, j3 = jj.y >> 16;
    int j4 = jj.z & 0xFFFF, j5 = jj.z >> 16;
    int j6 = jj.w & 0xFFFF, j7 = jj.w >> 16;
    float4 c0 = sortedg[molbaseS + j0];
    float4 c1 = sortedg[molbaseS + j1];
    float4 c2 = sortedg[molbaseS + j2];
    float4 c3 = sortedg[molbaseS + j3];
    float4 c4 = sortedg[molbaseS + j4];
    float4 c5 = sortedg[molbaseS + j5];
    float4 c6 = sortedg[molbaseS + j6];
    float4 c7 = sortedg[molbaseS + j7];
#define PROC(cj, jv)                                                        \
    {                                                                       \
      float d2 = fmaxf(__builtin_fmaf(mex, cj.x, __builtin_fmaf(mey, cj.y, \
                 __builtin_fmaf(mez, cj.z, mew + cj.w))), 0.f);             \
      u32 key = (__float_as_uint(d2) & KEYMASK) | (u32)(jv & 1023);         \
      int slot = cnt < NS ? cnt : (NS - 1);                                 \
      lists[slot * 256 + tid] = key;                                        \
      cnt += (d2 <= CUT2) ? 1 : 0;                                          \
    }
    PROC(c0, j0) PROC(c1, j1) PROC(c2, j2) PROC(c3, j3)
    PROC(c4, j4) PROC(c5, j5) PROC(c6, j6) PROC(c7, j7)
#undef PROC
  }
  if (cnt > NS) cnt = NS;

  // ---- phase 2: keys straight from LDS + bitonic sort 16 ----
  const u32 PADK = 0x7F800000u | (u32)spos;   // +inf self-pad, sorts last
  u32 r[32];
#pragma unroll
  for (int k = 0; k < 16; ++k)
    r[k] = (k < cnt) ? lists[k * 256 + tid] : PADK;
  bitonic_pass<16, 2, 1>(r);
  bitonic_pass<16, 4, 2>(r); bitonic_pass<16, 4, 1>(r);
  bitonic_pass<16, 8, 4>(r); bitonic_pass<16, 8, 2>(r); bitonic_pass<16, 8, 1>(r);
  bitonic_pass<16,16, 8>(r); bitonic_pass<16,16, 4>(r); bitonic_pass<16,16, 2>(r); bitonic_pass<16,16, 1>(r);

  // ---- phase 3a: symmetric pair merge (q0<->q1, q2<->q3), 16 keys ----
  __syncthreads();                       // lists/flat dead; lmem = publish buf
  {
    u32* myp = lmem + quarter * 1024 + ctr * 16;
#pragma unroll
    for (int k = 0; k < 16; ++k) myp[(k + ctr) & 15] = r[k];   // bank-swizzled
  }
  __syncthreads();
  if (!SPLIT || (quarter & 1) == 0) {    // SPLIT: only publishers need pair-32
    u32* op = lmem + (quarter ^ 1) * 1024 + ctr * 16;
#pragma unroll
    for (int i = 0; i < 16; ++i) r[16 + i] = op[((15 - i) + ctr) & 15]; // desc
    bitonic_pass<32,32,16>(r); bitonic_pass<32,32, 8>(r); bitonic_pass<32,32, 4>(r);
    bitonic_pass<32,32, 2>(r); bitonic_pass<32,32, 1>(r);
  }

  // ---- phase 3b: cross-pair merge ----
  __syncthreads();
  const int pairId = quarter >> 1;
  if ((quarter & 1) == 0) {
    u32* pp = lmem + pairId * 2048 + ctr * 32;
#pragma unroll
    for (int k = 0; k < 32; ++k) pp[(k + ctr) & 31] = r[k];
  }
  __syncthreads();
  if (!SPLIT || quarter == 0) {          // SPLIT: only q0 needs the final 32
    u32* opp = lmem + (1 - pairId) * 2048 + ctr * 32;
#pragma unroll
    for (int t = 0; t < 32; ++t) {
      u32 v = opp[((31 - t) + ctr) & 31];            // other pair, descending
      r[t] = r[t] < v ? r[t] : v;                    // lower half of bitonic-64
    }
    bitonic_pass<32,32,16>(r); bitonic_pass<32,32, 8>(r); bitonic_pass<32,32, 4>(r);
    bitonic_pass<32,32, 2>(r); bitonic_pass<32,32, 1>(r);
  }

  if constexpr (SPLIT) {
    // ---- phase 4 (split): q0 stores packed u16 keys, coalesced by spos ----
    if (quarter == 0) {
      u32 pk[16];
#pragma unroll
      for (int i = 0; i < 16; ++i) {
        u32 klo = r[2*i], khi = r[2*i+1];
        u32 plo = (((klo & KEYMASK) <= CUT2_BITS) ? 1024u : 0u) | (klo & 1023u);
        u32 phi = (((khi & KEYMASK) <= CUT2_BITS) ? 1024u : 0u) | (khi & 1023u);
        pk[i] = plo | (phi << 16);
      }
      uint4* kp = (uint4*)(keys + (size_t)(molbase + spos) * 32);
#pragma unroll
      for (int i = 0; i < 4; ++i)
        kp[i] = make_uint4(pk[4*i], pk[4*i+1], pk[4*i+2], pk[4*i+3]);
    }
    return;
  } else {
    // ---- phase 4 (mono fallback): scattered emit, one role per wave ----
    const int mloc = orig_s[spos];
    const int c = molbase + mloc;
    const long long E = (long long)NB * NM * NK;
    const float base = (float)molbase;
    const float nmex = -mex, nmey = -mey, nmez = -mez;

    if (quarter == 0) {                    // src + dst
      vf4* ps = (vf4*)(out       + (size_t)c * NK);
      vf4* pd = (vf4*)(out +   E + (size_t)c * NK);
      const float fc = (float)c;
      const vf4 dstv = {fc, fc, fc, fc};
#pragma unroll
      for (int q = 0; q < 8; ++q) {
        float sv[4];
#pragma unroll
        for (int u = 0; u < 4; ++u) {
          int idx = (int)(r[4*q + u] & 1023u);
          sv[u] = base + (float)orig_s[idx];
        }
        ps[q] = (vf4){sv[0], sv[1], sv[2], sv[3]};
        pd[q] = dstv;
      }
    } else if (quarter == 1) {             // weights
      vf4* pw = (vf4*)(out + 2*E + (size_t)c * NK);
#pragma unroll
      for (int q = 0; q < 8; ++q) {
        float wv[4];
#pragma unroll
        for (int u = 0; u < 4; ++u) {
          u32 key = r[4*q + u];
          int idx = (int)(key & 1023u);
          float4 cj = sortedg[molbaseS + idx];
          bool valid = (key & KEYMASK) <= CUT2_BITS;
          float vx = __builtin_fmaf(-0.5f, cj.x, nmex);
          float vy = __builtin_fmaf(-0.5f, cj.y, nmey);
          float vz = __builtin_fmaf(-0.5f, cj.z, nmez);
          bool wm  = valid && (idx != spos);
          float d2s = vx*vx + vy*vy + vz*vz;
          wv[u] = wm ? sqrtf(d2s) : 0.0f;
        }
        pw[q] = (vf4){wv[0], wv[1], wv[2], wv[3]};
      }
    } else if (quarter == 2) {             // edge vectors 0..15
      vf4* pv = (vf4*)(out + 3*E + (size_t)c * NK * 3);
#pragma unroll
      for (int q = 0; q < 4; ++q) {
        float vv[12];
#pragma unroll
        for (int u = 0; u < 4; ++u) {
          int idx = (int)(r[4*q + u] & 1023u);
          float4 cj = sortedg[molbaseS + idx];
          vv[3*u+0] = __builtin_fmaf(-0.5f, cj.x, nmex);
          vv[3*u+1] = __builtin_fmaf(-0.5f, cj.y, nmey);
          vv[3*u+2] = __builtin_fmaf(-0.5f, cj.z, nmez);
        }
        pv[3*q+0] = (vf4){vv[0], vv[1], vv[2],  vv[3]};
        pv[3*q+1] = (vf4){vv[4], vv[5], vv[6],  vv[7]};
        pv[3*q+2] = (vf4){vv[8], vv[9], vv[10], vv[11]};
      }
    } else {                               // edge vectors 16..31
      vf4* pv = (vf4*)(out + 3*E + (size_t)c * NK * 3) + 12;
#pragma unroll
      for (int q = 0; q < 4; ++q) {
        float vv[12];
#pragma unroll
        for (int u = 0; u < 4; ++u) {
          int idx = (int)(r[16 + 4*q + u] & 1023u);
          float4 cj = sortedg[molbaseS + idx];
          vv[3*u+0] = __builtin_fmaf(-0.5f, cj.x, nmex);
          vv[3*u+1] = __builtin_fmaf(-0.5f, cj.y, nmey);
          vv[3*u+2] = __builtin_fmaf(-0.5f, cj.z, nmez);
        }
        pv[3*q+0] = (vf4){vv[0], vv[1], vv[2],  vv[3]};
        pv[3*q+1] = (vf4){vv[4], vv[5], vv[6],  vv[7]};
        pv[3*q+2] = (vf4){vv[8], vv[9], vv[10], vv[11]};
      }
    }
  }
}

// Emit: one thread per EDGE. All stores instruction-coalesced:
// src/dst/w are 4B/lane contiguous, vec is 12B/lane contiguous. Loads:
// invpos+keys coalesced/broadcast, one 16B coord gather (L1/L2-warm).
__global__ __launch_bounds__(256) void emit_edges(const float4* __restrict__ sortedg,
                                                  const u16* __restrict__ origg,
                                                  const u16* __restrict__ invpos,
                                                  const u16* __restrict__ keys,
                                                  float* __restrict__ out)
{
  const int e = blockIdx.x * 256 + threadIdx.x;    // edge id
  const int r = e >> 5;                            // orig row (= dst id)
  const int k = e & 31;
  const int mb = r >> 10;
  const int molbase  = mb << 10;
  const int molbaseS = mb * SSTRIDE;
  const int spos = invpos[r];                      // broadcast within row

  const u16 key = keys[((size_t)(molbase + spos) << 5) + k];  // coalesced
  const int idx = (int)(key & 1023u);
  const bool valid = (key & 1024u) != 0;

  const float4 mc = sortedg[molbaseS + spos];      // broadcast within row
  const float4 cj = sortedg[molbaseS + idx];       // 16B gather, L1/L2-warm
  const float vx = (-0.5f*cj.x) - (-0.5f*mc.x);    // exact recovery, 1 rounding
  const float vy = (-0.5f*cj.y) - (-0.5f*mc.y);
  const float vz = (-0.5f*cj.z) - (-0.5f*mc.z);
  const bool wm = valid && (idx != spos);
  const float w = wm ? sqrtf(vx*vx + vy*vy + vz*vz) : 0.0f;

  const long long E = (long long)NB * NM * NK;
  out[e]       = (float)molbase + (float)origg[molbase + idx];  // src
  out[E + e]   = (float)r;                                      // dst
  out[2*E + e] = w;                                             // weight
  float* pv = out + 3*E + (size_t)e * 3;                        // vec
  pv[0] = vx; pv[1] = vy; pv[2] = vz;
}

extern "C" void kernel_launch(void* const* d_in, const int* in_sizes, int n_in,
                              void* d_out, int out_size, void* d_ws, size_t ws_size,
                              hipStream_t stream) {
  const float* pos = (const float*)d_in[0];
  float* out = (float*)d_out;
  float4* sortedg = (float4*)d_ws;
  u16* origid  = (u16*)((char*)d_ws + OFF_ORIG);
  u16* startsg = (u16*)((char*)d_ws + OFF_STARTS);
  u16* invpos  = (u16*)((char*)d_ws + OFF_INV);
  u16* keys    = (u16*)((char*)d_ws + OFF_KEYS);

  hipLaunchKernelGGL(pack_bin, dim3(NB), dim3(256), 0, stream,
                     pos, sortedg, origid, invpos, startsg);
  if (ws_size >= WS_NEEDED) {
    hipLaunchKernelGGL((radius_knn<true>), dim3(NB * (NM / 64)), dim3(256), 0, stream,
                       sortedg, origid, startsg, keys, out);
    hipLaunchKernelGGL(emit_edges, dim3((int)(((long long)NB * NM * NK) / 256)),
                       dim3(256), 0, stream, sortedg, origid, invpos, keys, out);
  } else {
    hipLaunchKernelGGL((radius_knn<false>), dim3(NB * (NM / 64)), dim3(256), 0, stream,
                       sortedg, origid, startsg, keys, out);
  }
}